// Round 11
// baseline (156.959 us; speedup 1.0000x reference)
//
#include <hip/hip_runtime.h>
#include <cstddef>

typedef float f4 __attribute__((ext_vector_type(4)));

#define OUT_FEATS 4096
#define IN_FEATS  16384
#define NCOL4     (IN_FEATS / 4)   // 4096 float4 per row
#define EPS       1e-8f

#define BT   256                   // threads per block (4 waves)
#define SW8  8                     // stripe width in f4 (32 floats = 128 B)
#define NBLK (NCOL4 / SW8)         // 512 blocks, 2 per CU
#define RG   (BT / SW8)            // 32 row-groups
#define KPT  (OUT_FEATS / RG)      // 128 rows per thread

// ---------------------------------------------------------------------------
// Column-stripe kernel (round-9/10 structure) + 32-row register carry.
// Grid = 512 blocks = 2/CU = 2 waves/SIMD, so up to 256 VGPR/wave is FREE.
// We use it: rows 96..127 (pc/pd/pe/pf, 128 VGPRs) stay live across the
// coeff reduction and are stored in phase 3 WITHOUT re-reading. Phase 3
// re-reads only rows 0..95: L2-level reads drop 537->469 MB.
//   phase 1: pipelined GEMV (pa/pb double-batch, first loads pre-barrier)
//   phase 2: 3x shfl_xor + one 32-entry LDS round, single barrier
//   phase 3: first two re-read batches issued BEFORE the carried stores
//            (reads overlap the store burst), then reverse-order pipelined
//            apply (MRU-first chases the MALL footprint; nt stores keep the
//            out stream from evicting A).
// Wave-load = 8 rows x 128 B = 8 cachelines/instr (fully-coalesced rate).
// ---------------------------------------------------------------------------
__global__ void __launch_bounds__(BT, 2)
k_fused(const f4* __restrict__ A4,
        const float* __restrict__ v,
        f4* __restrict__ out) {
    __shared__ float vs[OUT_FEATS];   // staged v (16 KiB)
    __shared__ f4    red[32];         // 4 waves x 8 col-slots
    __shared__ float dred[4];         // per-wave ||v||^2 partials

    const int T = threadIdx.x;
    const int q = T & (SW8 - 1);      // f4-column within stripe 0..7
    const int g = T >> 3;             // row-group 0..31
    const int w = T >> 6;             // wave 0..3
    const int c4 = blockIdx.x * SW8 + q;

    const size_t base = (size_t)g * NCOL4 + c4;
#define ROWOFF(k) (base + (size_t)(k) * RG * NCOL4)

    f4 pa[8], pb[8], pc[8], pd[8], pe[8], pf[8];

    // ---- issue first two A-batches before anything else ----
    #pragma unroll
    for (int u = 0; u < 8; ++u) pa[u] = A4[ROWOFF(u)];
    #pragma unroll
    for (int u = 0; u < 8; ++u) pb[u] = A4[ROWOFF(8 + u)];

    // ---- stage v into LDS + ||v||^2 ----
    float vsq = 0.f;
    {
        const f4* v4 = (const f4*)v;
        #pragma unroll
        for (int i = 0; i < OUT_FEATS / 4 / BT; ++i) {   // 4 iters
            const f4 x = v4[T + i * BT];
            ((f4*)vs)[T + i * BT] = x;
            vsq += x.x * x.x + x.y * x.y + x.z * x.z + x.w * x.w;
        }
    }
    #pragma unroll
    for (int off = 32; off > 0; off >>= 1) vsq += __shfl_down(vsq, off, 64);
    if ((T & 63) == 0) dred[w] = vsq;
    __syncthreads();
    const float denom = dred[0] + dred[1] + dred[2] + dred[3] + EPS;

    // ---- phase 1: pipelined GEMV over rows 0..95 ----
    f4 acc[8];
    #pragma unroll
    for (int u = 0; u < 8; ++u) acc[u] = 0.f;

    #pragma unroll
    for (int k0 = 0; k0 < 96; k0 += 16) {
        #pragma unroll
        for (int u = 0; u < 8; ++u)
            acc[u] += vs[g + (k0 + u) * RG] * pa[u];
        if (k0 + 16 < 96) {
            #pragma unroll
            for (int u = 0; u < 8; ++u) pa[u] = A4[ROWOFF(k0 + 16 + u)];
        }
        #pragma unroll
        for (int u = 0; u < 8; ++u)
            acc[u] += vs[g + (k0 + 8 + u) * RG] * pb[u];
        if (k0 + 24 < 96) {
            #pragma unroll
            for (int u = 0; u < 8; ++u) pb[u] = A4[ROWOFF(k0 + 24 + u)];
        }
    }

    // ---- carried tail: rows 96..127 load once, stay live to phase 3 ----
    #pragma unroll
    for (int u = 0; u < 8; ++u) pc[u] = A4[ROWOFF(96 + u)];
    #pragma unroll
    for (int u = 0; u < 8; ++u) pd[u] = A4[ROWOFF(104 + u)];
    #pragma unroll
    for (int u = 0; u < 8; ++u) pe[u] = A4[ROWOFF(112 + u)];
    #pragma unroll
    for (int u = 0; u < 8; ++u) pf[u] = A4[ROWOFF(120 + u)];
    #pragma unroll
    for (int u = 0; u < 8; ++u) acc[u] += vs[g + ( 96 + u) * RG] * pc[u];
    #pragma unroll
    for (int u = 0; u < 8; ++u) acc[u] += vs[g + (104 + u) * RG] * pd[u];
    #pragma unroll
    for (int u = 0; u < 8; ++u) acc[u] += vs[g + (112 + u) * RG] * pe[u];
    #pragma unroll
    for (int u = 0; u < 8; ++u) acc[u] += vs[g + (120 + u) * RG] * pf[u];

    f4 s = ((acc[0] + acc[1]) + (acc[2] + acc[3])) +
           ((acc[4] + acc[5]) + (acc[6] + acc[7]));

    // ---- phase 2: in-wave reduce (g-bits 3..5) + one LDS round ----
    #pragma unroll
    for (int off = 8; off <= 32; off <<= 1) {
        s.x += __shfl_xor(s.x, off, 64);
        s.y += __shfl_xor(s.y, off, 64);
        s.z += __shfl_xor(s.z, off, 64);
        s.w += __shfl_xor(s.w, off, 64);
    }
    if ((T & 63) < 8) red[w * 8 + (T & 7)] = s;
    __syncthreads();
    const f4 cf = (red[q] + red[q + 8] + red[q + 16] + red[q + 24]) / denom;

    // ---- phase 3: issue first re-read batches (rows 88..95, 80..87) ----
    #pragma unroll
    for (int u = 0; u < 8; ++u) pa[u] = A4[ROWOFF(88 + u)];
    #pragma unroll
    for (int u = 0; u < 8; ++u) pb[u] = A4[ROWOFF(80 + u)];

    // ---- carried stores: rows 120..127 down to 96..103, no re-read ----
    #pragma unroll
    for (int u = 0; u < 8; ++u)
        __builtin_nontemporal_store(pf[u] - vs[g + (120 + u) * RG] * cf,
                                    &out[ROWOFF(120 + u)]);
    #pragma unroll
    for (int u = 0; u < 8; ++u)
        __builtin_nontemporal_store(pe[u] - vs[g + (112 + u) * RG] * cf,
                                    &out[ROWOFF(112 + u)]);
    #pragma unroll
    for (int u = 0; u < 8; ++u)
        __builtin_nontemporal_store(pd[u] - vs[g + (104 + u) * RG] * cf,
                                    &out[ROWOFF(104 + u)]);
    #pragma unroll
    for (int u = 0; u < 8; ++u)
        __builtin_nontemporal_store(pc[u] - vs[g + ( 96 + u) * RG] * cf,
                                    &out[ROWOFF( 96 + u)]);

    // ---- pipelined reverse apply over rows 95..0 ----
    #pragma unroll
    for (int k0 = 88; k0 >= 8; k0 -= 16) {
        #pragma unroll
        for (int u = 0; u < 8; ++u)
            __builtin_nontemporal_store(pa[u] - vs[g + (k0 + u) * RG] * cf,
                                        &out[ROWOFF(k0 + u)]);
        if (k0 - 16 >= 0) {
            #pragma unroll
            for (int u = 0; u < 8; ++u) pa[u] = A4[ROWOFF(k0 - 16 + u)];
        }
        #pragma unroll
        for (int u = 0; u < 8; ++u)
            __builtin_nontemporal_store(pb[u] - vs[g + (k0 - 8 + u) * RG] * cf,
                                        &out[ROWOFF(k0 - 8 + u)]);
        if (k0 - 24 >= 0) {
            #pragma unroll
            for (int u = 0; u < 8; ++u) pb[u] = A4[ROWOFF(k0 - 24 + u)];
        }
    }
#undef ROWOFF
}

// ---------------------------------------------------------------------------
extern "C" void kernel_launch(void* const* d_in, const int* in_sizes, int n_in,
                              void* d_out, int out_size, void* d_ws, size_t ws_size,
                              hipStream_t stream) {
    const f4*    A4 = (const f4*)d_in[0];     // raw_update [4096, 16384] fp32
    const float* v  = (const float*)d_in[1];  // v [4096] fp32
    f4* out = (f4*)d_out;

    k_fused<<<NBLK, BT, 0, stream>>>(A4, v, out);
}

// Round 12
// 115.971 us; speedup vs baseline: 1.3534x; 1.3534x over previous
//
#include <hip/hip_runtime.h>
#include <cstddef>

typedef float f4 __attribute__((ext_vector_type(4)));

#define OUT_FEATS 4096
#define IN_FEATS  16384
#define NCOL4     (IN_FEATS / 4)   // 4096 float4 per row
#define EPS       1e-8f

#define BT   256                   // threads per block (4 waves)
#define SW8  8                     // stripe width in f4 (32 floats = 128 B)
#define NBLK (NCOL4 / SW8)         // 512 blocks, 2 per CU
#define RG   (BT / SW8)            // 32 row-groups
#define KPT  (OUT_FEATS / RG)      // 128 rows per thread

// ---------------------------------------------------------------------------
// Self-contained column-stripe kernel (round-10 optimum, reverted from the
// round-11 register-carry attempt which the allocator spilled to scratch:
// VGPR_Count=128 + 48 MB extra WRITE_SIZE = spill round-trip).
// Block b owns columns [32b, 32b+32):
//   phase 1: stream stripe (4096 x 128 B) -> coeff partials, double-batch
//            pipeline (pa/pb) so 8-16 loads stay in flight continuously;
//            first two batches issued BEFORE the v-staging barrier.
//   phase 2: 3 x shfl_xor in-wave reduce + one 32-entry LDS round, single
//            barrier; every thread computes its own coeff.
//   phase 3: reverse-order apply (MRU-first chases phase 1's MALL
//            footprint; nt stores keep out from evicting A). The last two
//            phase-1 batches (rows 112..127) are still live in pa/pb and
//            are stored WITHOUT re-reading; the pipeline refills behind.
// Wave-load = 8 rows x 128 B = 8 cachelines/instr (fully-coalesced rate).
// Measured: 116.0 us, FETCH 238 MB, WRITE 262 MB, no spill (VGPR 168).
// ---------------------------------------------------------------------------
__global__ void __launch_bounds__(BT)
k_fused(const f4* __restrict__ A4,
        const float* __restrict__ v,
        f4* __restrict__ out) {
    __shared__ float vs[OUT_FEATS];   // staged v (16 KiB)
    __shared__ f4    red[32];         // 4 waves x 8 col-slots
    __shared__ float dred[4];         // per-wave ||v||^2 partials

    const int T = threadIdx.x;
    const int q = T & (SW8 - 1);      // f4-column within stripe 0..7
    const int g = T >> 3;             // row-group 0..31
    const int w = T >> 6;             // wave 0..3
    const int c4 = blockIdx.x * SW8 + q;

    const size_t base = (size_t)g * NCOL4 + c4;
#define ROWOFF(k) (base + (size_t)(k) * RG * NCOL4)

    // ---- issue first two A-batches before anything else (HBM busy early) --
    f4 pa[8], pb[8];
    #pragma unroll
    for (int u = 0; u < 8; ++u) pa[u] = A4[ROWOFF(u)];
    #pragma unroll
    for (int u = 0; u < 8; ++u) pb[u] = A4[ROWOFF(8 + u)];

    // ---- stage v into LDS + ||v||^2 ----
    float vsq = 0.f;
    {
        const f4* v4 = (const f4*)v;
        #pragma unroll
        for (int i = 0; i < OUT_FEATS / 4 / BT; ++i) {   // 4 iters
            const f4 x = v4[T + i * BT];
            ((f4*)vs)[T + i * BT] = x;
            vsq += x.x * x.x + x.y * x.y + x.z * x.z + x.w * x.w;
        }
    }
    #pragma unroll
    for (int off = 32; off > 0; off >>= 1) vsq += __shfl_down(vsq, off, 64);
    if ((T & 63) == 0) dred[w] = vsq;
    __syncthreads();
    const float denom = dred[0] + dred[1] + dred[2] + dred[3] + EPS;

    // ---- phase 1: pipelined GEMV over own stripe ----
    f4 acc[8];
    #pragma unroll
    for (int u = 0; u < 8; ++u) acc[u] = 0.f;

    #pragma unroll
    for (int k = 0; k < KPT; k += 16) {
        #pragma unroll
        for (int u = 0; u < 8; ++u)
            acc[u] += vs[g + (k + u) * RG] * pa[u];        // consume batch k
        if (k + 16 < KPT) {
            #pragma unroll
            for (int u = 0; u < 8; ++u) pa[u] = A4[ROWOFF(k + 16 + u)];
        }
        #pragma unroll
        for (int u = 0; u < 8; ++u)
            acc[u] += vs[g + (k + 8 + u) * RG] * pb[u];    // consume batch k+8
        if (k + 24 < KPT) {
            #pragma unroll
            for (int u = 0; u < 8; ++u) pb[u] = A4[ROWOFF(k + 24 + u)];
        }
    }
    // after loop: pa = rows [112..119], pb = rows [120..127] (still live)
    f4 s = ((acc[0] + acc[1]) + (acc[2] + acc[3])) +
           ((acc[4] + acc[5]) + (acc[6] + acc[7]));

    // ---- phase 2: in-wave reduce (g-bits 3..5) + one LDS round ----
    #pragma unroll
    for (int off = 8; off <= 32; off <<= 1) {
        s.x += __shfl_xor(s.x, off, 64);
        s.y += __shfl_xor(s.y, off, 64);
        s.z += __shfl_xor(s.z, off, 64);
        s.w += __shfl_xor(s.w, off, 64);
    }
    if ((T & 63) < 8) red[w * 8 + (T & 7)] = s;
    __syncthreads();
    const f4 cf = (red[q] + red[q + 8] + red[q + 16] + red[q + 24]) / denom;

    // ---- phase 3: reverse-order apply + nt stores, pipelined ----
    // pb = rows [120..127] stored first (no re-read), pa = rows [112..119].
    #pragma unroll
    for (int k = KPT - 8; k >= 8; k -= 16) {
        #pragma unroll
        for (int u = 0; u < 8; ++u) {
            const int kk = k + u;
            __builtin_nontemporal_store(pb[u] - vs[g + kk * RG] * cf,
                                        &out[ROWOFF(kk)]);
        }
        if (k - 16 >= 0) {
            #pragma unroll
            for (int u = 0; u < 8; ++u) pb[u] = A4[ROWOFF(k - 16 + u)];
        }
        #pragma unroll
        for (int u = 0; u < 8; ++u) {
            const int kk = k - 8 + u;
            __builtin_nontemporal_store(pa[u] - vs[g + kk * RG] * cf,
                                        &out[ROWOFF(kk)]);
        }
        if (k - 24 >= 0) {
            #pragma unroll
            for (int u = 0; u < 8; ++u) pa[u] = A4[ROWOFF(k - 24 + u)];
        }
    }
#undef ROWOFF
}

// ---------------------------------------------------------------------------
extern "C" void kernel_launch(void* const* d_in, const int* in_sizes, int n_in,
                              void* d_out, int out_size, void* d_ws, size_t ws_size,
                              hipStream_t stream) {
    const f4*    A4 = (const f4*)d_in[0];     // raw_update [4096, 16384] fp32
    const float* v  = (const float*)d_in[1];  // v [4096] fp32
    f4* out = (f4*)d_out;

    k_fused<<<NBLK, BT, 0, stream>>>(A4, v, out);
}